// Round 3
// baseline (212.687 us; speedup 1.0000x reference)
//
#include <hip/hip_runtime.h>
#include <hip/hip_bf16.h>

#define SEQ 512
#define EMB 256
#define NHEAD 8
#define HD 32

using bf16x8 = __attribute__((ext_vector_type(8))) short;
using f32x4  = __attribute__((ext_vector_type(4))) float;

static __device__ __forceinline__ unsigned short f2bf(float x) {
    union { float f; unsigned int u; } v; v.f = x;
    unsigned int r = v.u + 0x7FFFu + ((v.u >> 16) & 1u);
    return (unsigned short)(r >> 16);
}
static __device__ __forceinline__ float bf2f(unsigned short v) {
    union { unsigned int u; float f; } w; w.u = ((unsigned int)v) << 16; return w.f;
}

// ---------------- prep: gather embeds, build masked-concat A (bf16) + query (bf16)
__global__ __launch_bounds__(256) void prep_kernel(
    const int* __restrict__ item_inputs,
    const int* __restrict__ label_inputs,
    const int* __restrict__ item_ids,
    const float* __restrict__ embeds,
    unsigned short* __restrict__ Abig,   // 16384 x 512 bf16
    unsigned short* __restrict__ qbf)    // 16384 x 256 bf16
{
    int t = threadIdx.x;
    int r = blockIdx.x * 2 + (t >> 7);
    int j = (t & 127) * 2;
    int item = item_inputs[r];
    int lab  = label_inputs[r];
    int qid  = item_ids[r];
    float2 e2 = *(const float2*)(embeds + (size_t)item * EMB + j);
    ushort2 on  = make_ushort2(f2bf(e2.x), f2bf(e2.y));
    ushort2 off = make_ushort2(0, 0);
    *(ushort2*)(Abig + (size_t)r * 512 + j)       = lab ? on : off;
    *(ushort2*)(Abig + (size_t)r * 512 + 256 + j) = lab ? off : on;
    float2 q2 = *(const float2*)(embeds + (size_t)qid * EMB + j);
    *(ushort2*)(qbf + (size_t)r * 256 + j) = make_ushort2(f2bf(q2.x), f2bf(q2.y));
}

// ---------------- merged weight prep: WTin, WTq, WTk transposes + Wvw/bvw folds
__global__ __launch_bounds__(256) void wcombo_kernel(
    const float* __restrict__ W_in,
    const float* __restrict__ Wq,
    const float* __restrict__ Wk,
    const float* __restrict__ Wv,
    const float* __restrict__ Wout,
    const float* __restrict__ bv,
    unsigned short* __restrict__ WTin,   // 256 x 512
    unsigned short* __restrict__ WTq,    // 256 x 256
    unsigned short* __restrict__ WTk,    // 256 x 256
    float* __restrict__ Wvw,             // 256 x 8
    float* __restrict__ bvw)             // 8
{
    int idx = blockIdx.x * 256 + threadIdx.x;
    if (idx < 131072) {                       // WTin[n][k] = W_in[k][n], K=512
        int n = idx >> 9, k = idx & 511;
        WTin[idx] = f2bf(W_in[(size_t)k * 256 + n]);
    } else if (idx < 196608) {                // WTq, K=256
        int i = idx - 131072;
        int n = i >> 8, k = i & 255;
        WTq[i] = f2bf(Wq[(size_t)k * 256 + n]);
    } else if (idx < 262144) {                // WTk, K=256
        int i = idx - 196608;
        int n = i >> 8, k = i & 255;
        WTk[i] = f2bf(Wk[(size_t)k * 256 + n]);
    } else if (idx < 264192) {                // Wvw[c][h] = sum_d Wv[c][32h+d]*Wout[32h+d]
        int i = idx - 262144;
        int c = i >> 3, h = i & 7;
        float s = 0.f;
        #pragma unroll
        for (int d = 0; d < 32; d++) s += Wv[(size_t)c * 256 + h * 32 + d] * Wout[h * 32 + d];
        Wvw[i] = s;
    } else if (idx < 264200) {                // bvw[h]
        int h = idx - 264192;
        float s = 0.f;
        #pragma unroll
        for (int d = 0; d < 32; d++) s += bv[h * 32 + d] * Wout[h * 32 + d];
        bvw[h] = s;
    }
}

// ---------------- MFMA GEMM body: C(M x 256) = A(M x KDIM) * BT^T + bias
template<int KDIM, int RELU, int OUTBF>
static __device__ __forceinline__ void gemm_body(
    const unsigned short* __restrict__ A,
    const unsigned short* __restrict__ BT,
    const float* __restrict__ bias,
    void* __restrict__ Cout, float scale)
{
    __shared__ unsigned short As[64][40];
    __shared__ unsigned short Bs[128][40];
    const int t = threadIdx.x;
    const int row0 = blockIdx.x * 64;
    const int col0 = blockIdx.y * 128;
    const int wid = t >> 6, lane = t & 63;
    const int wm = wid & 1, wn = wid >> 1;
    const int lg = lane >> 4, l15 = lane & 15;

    f32x4 acc[2][4];
    #pragma unroll
    for (int i = 0; i < 2; i++)
        #pragma unroll
        for (int j = 0; j < 4; j++) acc[i][j] = (f32x4){0.f, 0.f, 0.f, 0.f};

    const int arow = t >> 2, achk = t & 3;
    const int brow = t >> 1, bhalf = t & 1;

    for (int k0 = 0; k0 < KDIM; k0 += 32) {
        __syncthreads();
        *(uint4*)(&As[arow][achk * 8]) =
            *(const uint4*)(A + (size_t)(row0 + arow) * KDIM + k0 + achk * 8);
        const unsigned short* bsrc = BT + (size_t)(col0 + brow) * KDIM + k0 + bhalf * 16;
        *(uint4*)(&Bs[brow][bhalf * 16])     = *(const uint4*)(bsrc);
        *(uint4*)(&Bs[brow][bhalf * 16 + 8]) = *(const uint4*)(bsrc + 8);
        __syncthreads();
        bf16x8 af[2], bfr[4];
        #pragma unroll
        for (int fm = 0; fm < 2; fm++)
            af[fm] = *(const bf16x8*)(&As[wm * 32 + fm * 16 + l15][lg * 8]);
        #pragma unroll
        for (int fn = 0; fn < 4; fn++)
            bfr[fn] = *(const bf16x8*)(&Bs[wn * 64 + fn * 16 + l15][lg * 8]);
        #pragma unroll
        for (int fm = 0; fm < 2; fm++)
            #pragma unroll
            for (int fn = 0; fn < 4; fn++)
                acc[fm][fn] = __builtin_amdgcn_mfma_f32_16x16x32_bf16(
                    af[fm], bfr[fn], acc[fm][fn], 0, 0, 0);
    }
    #pragma unroll
    for (int fm = 0; fm < 2; fm++)
        #pragma unroll
        for (int fn = 0; fn < 4; fn++) {
            int col = col0 + wn * 64 + fn * 16 + l15;
            float bvv = bias[col];
            #pragma unroll
            for (int r = 0; r < 4; r++) {
                int row = row0 + wm * 32 + fm * 16 + lg * 4 + r;
                float v = acc[fm][fn][r] + bvv;
                if (RELU) v = fmaxf(v, 0.f);
                v *= scale;
                if (OUTBF) ((unsigned short*)Cout)[(size_t)row * 256 + col] = f2bf(v);
                else       ((float*)Cout)[(size_t)row * 256 + col] = v;
            }
        }
}

__global__ __launch_bounds__(256, 2) void gemm512_kernel(
    const unsigned short* __restrict__ A,
    const unsigned short* __restrict__ BT,
    const float* __restrict__ bias,
    unsigned short* __restrict__ Cout)
{
    gemm_body<512, 1, 1>(A, BT, bias, (void*)Cout, 1.0f);
}

// ---------------- Vw body: Vw[row][h] = X[row]·Wvw[:,h] + bvw[h]
static __device__ __forceinline__ void vw_body(
    const unsigned short* __restrict__ Xbf,
    const float* __restrict__ Wvw,
    const float* __restrict__ bvw,
    float* __restrict__ Vw)
{
    __shared__ float sW[2048];
    __shared__ float sb[8];
    int t = threadIdx.x;
    #pragma unroll
    for (int i = 0; i < 8; i++) sW[i * 256 + t] = Wvw[i * 256 + t];
    if (t < 8) sb[t] = bvw[t];
    __syncthreads();
    int row = blockIdx.x * 256 + t;
    float acc[8];
    #pragma unroll
    for (int h = 0; h < 8; h++) acc[h] = sb[h];
    for (int d0 = 0; d0 < 32; d0++) {
        bf16x8 x = *(const bf16x8*)(Xbf + (size_t)row * 256 + d0 * 8);
        #pragma unroll
        for (int j = 0; j < 8; j++) {
            float xf = bf2f((unsigned short)x[j]);
            #pragma unroll
            for (int h = 0; h < 8; h++) acc[h] += xf * sW[(d0 * 8 + j) * 8 + h];
        }
    }
    *(float4*)(Vw + (size_t)row * 8)     = make_float4(acc[0], acc[1], acc[2], acc[3]);
    *(float4*)(Vw + (size_t)row * 8 + 4) = make_float4(acc[4], acc[5], acc[6], acc[7]);
}

// ---------------- fused Q-GEMM / K-GEMM / Vw in one launch (z selects)
__global__ __launch_bounds__(256, 2) void gemmQKV_kernel(
    const unsigned short* __restrict__ qbf,
    const unsigned short* __restrict__ WTq,
    const float* __restrict__ bq,
    unsigned short* __restrict__ Qbf,
    const unsigned short* __restrict__ Xbf,
    const unsigned short* __restrict__ WTk,
    const float* __restrict__ bk,
    unsigned short* __restrict__ Kbf,
    const float* __restrict__ Wvw,
    const float* __restrict__ bvw,
    float* __restrict__ Vw)
{
    if (blockIdx.z == 0) {
        gemm_body<256, 0, 1>(qbf, WTq, bq, (void*)Qbf, 0.17677669529663687f);
    } else if (blockIdx.z == 1) {
        gemm_body<256, 0, 1>(Xbf, WTk, bk, (void*)Kbf, 1.0f);
    } else {
        if (blockIdx.x >= 64 || blockIdx.y != 0) return;
        vw_body(Xbf, Wvw, bvw, Vw);
    }
}

// ---------------- fused attention v3: 8 waves split kt tiles; ET/ER in-register
__global__ __launch_bounds__(512, 4) void attn3_kernel(
    const unsigned short* __restrict__ Qbf,
    const unsigned short* __restrict__ Kbf,
    const float* __restrict__ Vw,
    const float* __restrict__ rel,
    const float* __restrict__ tsp,
    const float* __restrict__ bout,
    const float* __restrict__ pl1,
    const float* __restrict__ pl2,
    float* __restrict__ logits,
    float* __restrict__ attn)
{
    __shared__ float sden[8][8][32];   // [wave][head][q] partial denp
    __shared__ float sdt[8][32];
    __shared__ float sdr[8][32];
    __shared__ float sinv[8][32];      // 1/denp per head,q
    __shared__ float sinvt[32];
    __shared__ float sinvr[32];
    __shared__ float slog[8][32];

    const int t = threadIdx.x;
    const int id = blockIdx.x;
    const int b  = id & 31;            // same-b blocks land on same XCD (id%8 == b%8)
    const int qt = 15 - (id >> 5);     // heavy q-tiles dispatched first
    const int q0 = qt * 32;
    const int w = t >> 6;
    const int lane = t & 63;
    const int l15 = lane & 15, lg = lane >> 4;
    const int ntile = qt + 1;

    const float l1 = pl1[0], l2 = pl2[0];
    const float cp = (1.f - l1) * (1.f - l2);
    const float ct = (1.f - l1) * l2;
    const float cr = l1;

    // ---------- phase 1a: dent/denr partials over this wave's kt tiles ----------
    float dt[2][4] = {{0,0,0,0},{0,0,0,0}};
    float dr[2][4] = {{0,0,0,0},{0,0,0,0}};
    #pragma unroll 1
    for (int kt = w; kt < ntile; kt += 8) {
        const int k0 = kt * 32;
        #pragma unroll
        for (int mf = 0; mf < 2; mf++)
            #pragma unroll
            for (int r = 0; r < 4; r++) {
                const int qrow = q0 + mf * 16 + lg * 4 + r;
                const size_t base = ((size_t)(b * SEQ) + qrow) * SEQ + k0 + l15;
                #pragma unroll
                for (int nf = 0; nf < 2; nf++) {
                    const int kcol = k0 + nf * 16 + l15;
                    const bool va = kcol <= qrow;
                    float tv = tsp[base + nf * 16];
                    float rv = rel[base + nf * 16];
                    dt[mf][r] += va ? __expf(__expf(-fabsf(tv))) : 0.f;
                    dr[mf][r] += (va && rv != 0.f) ? __expf(rv) : 0.f;
                }
            }
    }
    #pragma unroll
    for (int mf = 0; mf < 2; mf++)
        #pragma unroll
        for (int r = 0; r < 4; r++) {
            float v = dt[mf][r];
            v += __shfl_xor(v, 1); v += __shfl_xor(v, 2);
            v += __shfl_xor(v, 4); v += __shfl_xor(v, 8);
            dt[mf][r] = v;
            float u = dr[mf][r];
            u += __shfl_xor(u, 1); u += __shfl_xor(u, 2);
            u += __shfl_xor(u, 4); u += __shfl_xor(u, 8);
            dr[mf][r] = u;
        }
    if (l15 == 0) {
        #pragma unroll
        for (int mf = 0; mf < 2; mf++)
            #pragma unroll
            for (int r = 0; r < 4; r++) {
                sdt[w][mf * 16 + lg * 4 + r] = dt[mf][r];
                sdr[w][mf * 16 + lg * 4 + r] = dr[mf][r];
            }
    }

    // ---------- phase 1b: denp partials, head-at-a-time ----------
    #pragma unroll 1
    for (int h = 0; h < 8; h++) {
        bf16x8 aq0 = *(const bf16x8*)(Qbf + ((size_t)(b * SEQ + q0 + l15)) * EMB + h * 32 + lg * 8);
        bf16x8 aq1 = *(const bf16x8*)(Qbf + ((size_t)(b * SEQ + q0 + 16 + l15)) * EMB + h * 32 + lg * 8);
        float dp[2][4] = {{0,0,0,0},{0,0,0,0}};
        #pragma unroll 1
        for (int kt = w; kt < ntile; kt += 8) {
            const int k0 = kt * 32;
            #pragma unroll
            for (int nf = 0; nf < 2; nf++) {
                bf16x8 bk = *(const bf16x8*)(Kbf +
                    ((size_t)(b * SEQ + k0 + nf * 16 + l15)) * EMB + h * 32 + lg * 8);
                const int kcol = k0 + nf * 16 + l15;
                f32x4 a0 = __builtin_amdgcn_mfma_f32_16x16x32_bf16(aq0, bk, (f32x4){0,0,0,0}, 0, 0, 0);
                f32x4 a1 = __builtin_amdgcn_mfma_f32_16x16x32_bf16(aq1, bk, (f32x4){0,0,0,0}, 0, 0, 0);
                #pragma unroll
                for (int r = 0; r < 4; r++) {
                    const int qr0 = q0 + lg * 4 + r;
                    dp[0][r] += (kcol <= qr0) ? __expf(a0[r]) : 0.f;
                    dp[1][r] += (kcol <= qr0 + 16) ? __expf(a1[r]) : 0.f;
                }
            }
        }
        #pragma unroll
        for (int mf = 0; mf < 2; mf++)
            #pragma unroll
            for (int r = 0; r < 4; r++) {
                float v = dp[mf][r];
                v += __shfl_xor(v, 1); v += __shfl_xor(v, 2);
                v += __shfl_xor(v, 4); v += __shfl_xor(v, 8);
                if (l15 == 0) sden[w][h][mf * 16 + lg * 4 + r] = v;
            }
    }
    __syncthreads();
    if (t < 256) {
        const int h = t >> 5, q = t & 31;
        float s = 0.f;
        #pragma unroll
        for (int ww = 0; ww < 8; ww++) s += sden[ww][h][q];
        sinv[h][q] = 1.f / s;
        if (h == 0) {
            float s2 = 0.f, s3 = 0.f;
            #pragma unroll
            for (int ww = 0; ww < 8; ww++) { s2 += sdt[ww][q]; s3 += sdr[ww][q]; }
            sinvt[q] = 1.f / s2;
            sinvr[q] = s3 > 0.f ? 1.f / s3 : 0.f;
        }
    }
    __syncthreads();

    // ---------- phase 2: blend + write attn + logits partials ----------
    float plog[2][4] = {{0,0,0,0},{0,0,0,0}};
    #pragma unroll 1
    for (int kt = w; kt < ntile; kt += 8) {
        const int k0 = kt * 32;
        float et[2][4][2], er[2][4][2];
        #pragma unroll
        for (int mf = 0; mf < 2; mf++)
            #pragma unroll
            for (int r = 0; r < 4; r++) {
                const int qrow = q0 + mf * 16 + lg * 4 + r;
                const size_t base = ((size_t)(b * SEQ) + qrow) * SEQ + k0 + l15;
                #pragma unroll
                for (int nf = 0; nf < 2; nf++) {
                    const int kcol = k0 + nf * 16 + l15;
                    const bool va = kcol <= qrow;
                    float tv = tsp[base + nf * 16];
                    float rv = rel[base + nf * 16];
                    et[mf][r][nf] = va ? __expf(__expf(-fabsf(tv))) : 0.f;
                    er[mf][r][nf] = (va && rv != 0.f) ? __expf(rv) : 0.f;
                }
            }
        #pragma unroll 1
        for (int h = 0; h < 8; h++) {
            bf16x8 aq0 = *(const bf16x8*)(Qbf + ((size_t)(b * SEQ + q0 + l15)) * EMB + h * 32 + lg * 8);
            bf16x8 aq1 = *(const bf16x8*)(Qbf + ((size_t)(b * SEQ + q0 + 16 + l15)) * EMB + h * 32 + lg * 8);
            #pragma unroll
            for (int nf = 0; nf < 2; nf++) {
                const int kcol = k0 + nf * 16 + l15;
                bf16x8 bk = *(const bf16x8*)(Kbf +
                    ((size_t)(b * SEQ + kcol)) * EMB + h * 32 + lg * 8);
                const float vwv = Vw[((size_t)(b * SEQ + kcol)) * 8 + h];
                f32x4 am[2];
                am[0] = __builtin_amdgcn_mfma_f32_16x16x32_bf16(aq0, bk, (f32x4){0,0,0,0}, 0, 0, 0);
                am[1] = __builtin_amdgcn_mfma_f32_16x16x32_bf16(aq1, bk, (f32x4){0,0,0,0}, 0, 0, 0);
                #pragma unroll
                for (int mf = 0; mf < 2; mf++)
                    #pragma unroll
                    for (int r = 0; r < 4; r++) {
                        const int qloc = mf * 16 + lg * 4 + r;
                        const int qrow = q0 + qloc;
                        float a = 0.f;
                        if (kcol <= qrow)
                            a = cp * __expf(am[mf][r]) * sinv[h][qloc]
                              + ct * et[mf][r][nf] * sinvt[qloc]
                              + cr * er[mf][r][nf] * sinvr[qloc];
                        attn[((size_t)((b * NHEAD + h) * SEQ) + qrow) * SEQ + kcol] = a;
                        plog[mf][r] = fmaf(a, vwv, plog[mf][r]);
                    }
            }
        }
    }

    // ---------- zero-fill strictly-future tiles (split over waves) ----------
    {
        const int nz = 15 - qt;
        const int zrow = lane >> 1;
        const int zc = (lane & 1) * 16;
        const float4 z4 = make_float4(0.f, 0.f, 0.f, 0.f);
        #pragma unroll 1
        for (int zi = w; zi < nz; zi += 8) {
            const int k0 = (qt + 1 + zi) * 32;
            #pragma unroll
            for (int h = 0; h < NHEAD; h++) {
                float4* p = (float4*)(attn +
                    ((size_t)((b * NHEAD + h) * SEQ) + q0 + zrow) * SEQ + k0 + zc);
                p[0] = z4; p[1] = z4; p[2] = z4; p[3] = z4;
            }
        }
    }

    // ---------- logits reduce ----------
    #pragma unroll
    for (int mf = 0; mf < 2; mf++)
        #pragma unroll
        for (int r = 0; r < 4; r++) {
            float v = plog[mf][r];
            v += __shfl_xor(v, 1); v += __shfl_xor(v, 2);
            v += __shfl_xor(v, 4); v += __shfl_xor(v, 8);
            if (l15 == 0) slog[w][mf * 16 + lg * 4 + r] = v;
        }
    __syncthreads();
    if (t < 32) {
        float s = bout[0];
        #pragma unroll
        for (int ww = 0; ww < 8; ww++) s += slog[ww][t];
        logits[b * SEQ + q0 + t] = s;
    }
}

// ---------------- host launch ----------------
extern "C" void kernel_launch(void* const* d_in, const int* in_sizes, int n_in,
                              void* d_out, int out_size, void* d_ws, size_t ws_size,
                              hipStream_t stream)
{
    (void)in_sizes; (void)n_in; (void)out_size; (void)ws_size;
    const int*   item_inputs  = (const int*)d_in[0];
    const int*   label_inputs = (const int*)d_in[1];
    const int*   item_ids     = (const int*)d_in[2];
    const float* rel   = (const float*)d_in[3];
    const float* tsp   = (const float*)d_in[4];
    const float* emb   = (const float*)d_in[5];
    const float* W_in  = (const float*)d_in[6];
    const float* b_in  = (const float*)d_in[7];
    const float* Wq    = (const float*)d_in[8];
    const float* bq    = (const float*)d_in[9];
    const float* Wk    = (const float*)d_in[10];
    const float* bk    = (const float*)d_in[11];
    const float* Wv    = (const float*)d_in[12];
    const float* bv    = (const float*)d_in[13];
    const float* Wout  = (const float*)d_in[14];
    const float* bout  = (const float*)d_in[15];
    const float* l1    = (const float*)d_in[16];
    const float* l2    = (const float*)d_in[17];

    const size_t R = 16384;
    char* w = (char*)d_ws;
    unsigned short* Abig = (unsigned short*)w; w += R * 512 * 2;
    unsigned short* qbf  = (unsigned short*)w; w += R * 256 * 2;
    unsigned short* WTin = (unsigned short*)w; w += (size_t)256 * 512 * 2;
    unsigned short* WTq  = (unsigned short*)w; w += (size_t)256 * 256 * 2;
    unsigned short* WTk  = (unsigned short*)w; w += (size_t)256 * 256 * 2;
    unsigned short* Xbf  = (unsigned short*)w; w += R * 256 * 2;
    unsigned short* Qbf  = (unsigned short*)w; w += R * 256 * 2;
    unsigned short* Kbf  = (unsigned short*)w; w += R * 256 * 2;
    float* Wvw = (float*)w; w += 2048 * 4;
    float* Vw  = (float*)w; w += R * 8 * 4;
    float* bvw = (float*)w; w += 256;

    prep_kernel<<<dim3(8192), dim3(256), 0, stream>>>(
        item_inputs, label_inputs, item_ids, emb, Abig, qbf);
    wcombo_kernel<<<dim3(1033), dim3(256), 0, stream>>>(
        W_in, Wq, Wk, Wv, Wout, bv, WTin, WTq, WTk, Wvw, bvw);

    gemm512_kernel<<<dim3(256, 2), dim3(256), 0, stream>>>(Abig, WTin, b_in, Xbf);
    gemmQKV_kernel<<<dim3(256, 2, 3), dim3(256), 0, stream>>>(
        qbf, WTq, bq, Qbf, Xbf, WTk, bk, Kbf, Wvw, bvw, Vw);

    float* logits = (float*)d_out;
    float* attnp  = (float*)d_out + 16384;
    attn3_kernel<<<dim3(512), dim3(512), 0, stream>>>(
        Qbf, Kbf, Vw, rel, tsp, bout, l1, l2, logits, attnp);
}